// Round 1
// baseline (133.797 us; speedup 1.0000x reference)
//
#include <hip/hip_runtime.h>
#include <stdint.h>

#define NPIX 9216   // 96*96
#define NIMG 32
#define STRIP 1152  // NPIX / 8 strips

// ---------- JAX threefry2x32 (20 rounds), bit-exact (verified rounds 1-12) ----------
__device__ __forceinline__ uint32_t rotl32(uint32_t x, int d){ return (x<<d)|(x>>(32-d)); }

__device__ __forceinline__ void threefry(uint32_t k0, uint32_t k1, uint32_t x0, uint32_t x1,
                                         uint32_t &o0, uint32_t &o1){
  uint32_t ks2 = k0 ^ k1 ^ 0x1BD11BDAu;
  x0 += k0; x1 += k1;
  x0+=x1; x1=rotl32(x1,13); x1^=x0;
  x0+=x1; x1=rotl32(x1,15); x1^=x0;
  x0+=x1; x1=rotl32(x1,26); x1^=x0;
  x0+=x1; x1=rotl32(x1,6);  x1^=x0;
  x0+=k1; x1+=ks2+1u;
  x0+=x1; x1=rotl32(x1,17); x1^=x0;
  x0+=x1; x1=rotl32(x1,29); x1^=x0;
  x0+=x1; x1=rotl32(x1,16); x1^=x0;
  x0+=x1; x1=rotl32(x1,24); x1^=x0;
  x0+=ks2; x1+=k0+2u;
  x0+=x1; x1=rotl32(x1,13); x1^=x0;
  x0+=x1; x1=rotl32(x1,15); x1^=x0;
  x0+=x1; x1=rotl32(x1,26); x1^=x0;
  x0+=x1; x1=rotl32(x1,6);  x1^=x0;
  x0+=k0; x1+=k1+3u;
  x0+=x1; x1=rotl32(x1,17); x1^=x0;
  x0+=x1; x1=rotl32(x1,29); x1^=x0;
  x0+=x1; x1=rotl32(x1,16); x1^=x0;
  x0+=x1; x1=rotl32(x1,24); x1^=x0;
  x0+=k1; x1+=ks2+4u;
  x0+=x1; x1=rotl32(x1,13); x1^=x0;
  x0+=x1; x1=rotl32(x1,15); x1^=x0;
  x0+=x1; x1=rotl32(x1,26); x1^=x0;
  x0+=x1; x1=rotl32(x1,6);  x1^=x0;
  x0+=ks2; x1+=k0+5u;
  o0=x0; o1=x1;
}

__device__ __forceinline__ float clip01_div255(float x){
  return fminf(fmaxf(x/255.0f, 0.0f), 1.0f);
}

// ---------- K1: 512 blocks = img x cls x 8 strips.
// Now ALSO computes the per-image channel max inline (fused former kmax; fmax is
// order-independent so the fold is bit-exact). LDS staging, VALID-ONLY histogram,
// exact local top-50; bbin via single-wave shfl suffix scan.
// XCD-contiguous swizzle: image I's 16 blocks land on XCD I/4 -> its L2 holds 4 imgs.
__global__ __launch_bounds__(256) void kscore(const float* __restrict__ in,
                                              unsigned long long* __restrict__ key50g){
#pragma clang fp contract(off)
  int b   = (blockIdx.x & 7)*64 + (blockIdx.x >> 3);   // bijective (512 = 8*64)
  int img = b >> 4, cls = (b >> 3) & 1, sub = b & 7;
  int tid = threadIdx.x;

  __shared__ __attribute__((aligned(16))) float pixL[3456];  // strip pixels
  __shared__ uint32_t vvL[STRIP];
  __shared__ uint64_t cand[STRIP];
  __shared__ int hist[129];
  __shared__ int ncand, bbin;
  __shared__ float rmx[3][4];

  if(tid<129) hist[tid]=0;
  if(tid==0)  ncand=0;

  const float* p = in + (size_t)img*NPIX*3;

  // stage own strip (864 float4, coalesced)
  const float4* sp4 = (const float4*)(p + (size_t)sub*STRIP*3);
  float4* pixL4 = (float4*)pixL;
  for(int k=0;k<4;k++){ int i4=k*256+tid; if(i4<864) pixL4[i4]=sp4[i4]; }

  // image channel max: full-image scan from L2 (replaces kmax kernel).
  // 6912 float4 / 256 threads = 27 each. Channel of elem 4*i4+e is ((i4%3)+e)%3.
  float m0=0.f, m1=0.f, m2=0.f;
  const float4* ip4 = (const float4*)p;
  for(int k=0;k<27;k++){
    int i4 = k*256 + tid;
    float4 v = ip4[i4];
    float e0=clip01_div255(v.x), e1=clip01_div255(v.y),
          e2=clip01_div255(v.z), e3=clip01_div255(v.w);
    int b3 = i4 % 3;
    float cb = fmaxf(e0,e3);                       // e0,e3 share channel b3
    m0 = fmaxf(m0, b3==0 ? cb : (b3==1 ? e2 : e1));
    m1 = fmaxf(m1, b3==0 ? e1 : (b3==1 ? cb : e2));
    m2 = fmaxf(m2, b3==0 ? e2 : (b3==1 ? e1 : cb));
  }
  for(int off=32; off>0; off>>=1){
    m0 = fmaxf(m0, __shfl_down(m0,off));
    m1 = fmaxf(m1, __shfl_down(m1,off));
    m2 = fmaxf(m2, __shfl_down(m2,off));
  }
  { int lane = tid & 63, wv = tid >> 6;
    if(lane==0){ rmx[0][wv]=m0; rmx[1][wv]=m1; rmx[2][wv]=m2; } }

  // partitionable threefry keys (bit-exact)
  uint32_t ik0, ik1; threefry(0u, 42u, 0u, (uint32_t)img, ik0, ik1);
  uint32_t s0, s1;   threefry(ik0, ik1, 0u, (uint32_t)cls, s0, s1);
  __syncthreads();   // covers pixL staging + rmx writes

  float c0 = fmaxf(fmaxf(rmx[0][0],rmx[0][1]), fmaxf(rmx[0][2],rmx[0][3]));
  float c1 = fmaxf(fmaxf(rmx[1][0],rmx[1][1]), fmaxf(rmx[1][2],rmx[1][3]));
  float c2 = fmaxf(fmaxf(rmx[2][0],rmx[2][1]), fmaxf(rmx[2][2],rmx[2][3]));

  // score strip + histogram (math bit-identical); valid-only adds
  for(int r=0;r<5;r++){
    int pi = tid + r*256;
    if(pi<STRIP){
      float a  = clip01_div255(pixL[pi*3+0])/c0;
      float bb = clip01_div255(pixL[pi*3+1])/c1;
      float c  = clip01_div255(pixL[pi*3+2])/c2;
      bool fg = (a>0.f && a<0.6f) || (bb>0.f && bb<0.6f) || (c>0.f && c<0.6f);
      bool valid = (cls==0) ? fg : !fg;
      uint32_t gi = (uint32_t)(sub*STRIP + pi);
      uint32_t r1,r2; threefry(s0, s1, 0u, gi, r1, r2);
      uint32_t vv = valid ? ((r1 ^ r2) >> 9) + 1u : 0u;  // monotone in uniform; 0 = invalid(-1.0)
      vvL[pi] = vv;
      if(vv) atomicAdd(&hist[vv>>16], 1);   // hist[0] never counted
    }
  }
  __syncthreads();

  // bbin = largest bin with suffix-count >= 50 (single-wave shfl suffix scan)
  if(tid < 64){
    int h0 = hist[2*tid];
    int h1 = hist[2*tid+1];
    int h128 = hist[128];
    int S = h0 + h1;
    for(int off=1; off<64; off<<=1){
      int o = __shfl_down(S, off);
      if(tid + off < 64) S += o;
    }
    int ss0 = S + h128;
    int ss1 = S - h0 + h128;
    int cd = -1;
    if(ss0 >= 50) cd = 2*tid;
    if(ss1 >= 50) cd = 2*tid+1;
    if(tid==63 && h128 >= 50) cd = 128;
    for(int off=32; off>0; off>>=1){
      int o = __shfl_down(cd, off);
      cd = o > cd ? o : cd;
    }
    if(tid==0) bbin = cd;
  }
  __syncthreads();

  int bb = bbin;
  for(int r=0;r<5;r++){
    int pi = tid + r*256;
    if(pi<STRIP){
      uint32_t vv = vvL[pi];
      if((int)(vv>>16) >= bb){
        int pos = atomicAdd(&ncand,1);
        cand[pos] = ((uint64_t)vv << 14) | (uint64_t)(16383 - (sub*STRIP + pi));  // higher = earlier
      }
    }
  }
  __syncthreads();
  int m = ncand;
  for(int c=tid;c<m;c+=256){
    uint64_t k = cand[c];
    int r = 0, j = 0;
    while(j < m){                        // chunked early-exit: exact for r<50
      int je = j+64 < m ? j+64 : m;
      for(; j<je; j++) r += (cand[j] > k);
      if(r >= 50) break;
    }
    if(r < 50) key50g[(size_t)b*50 + r] = k;  // rank r -> descending sorted list
  }
}

// ---------- K2: 1152 blocks = img x 36 chunks. Fused merge+knn:
// each block redundantly merges the 16 strip lists of its image (binary-search
// ranks over 8 descending 50-lists per class), rebuilds train features + stats
// with the EXACT same serial summation order (bit-identical standardization),
// then runs the 5-NN packed-pair min/max insertion networks for its 256 pixels.
// XCD-contiguous swizzle: image I's 36 blocks -> XCD I/4.
__global__ __launch_bounds__(256) void kmknn(const float* __restrict__ in,
                                             const unsigned long long* __restrict__ key50g,
                                             float* __restrict__ out){
#pragma clang fp contract(off)
  int b     = (blockIdx.x & 7)*144 + (blockIdx.x >> 3);  // bijective (1152 = 8*144)
  int img   = b / 36;
  int chunk = b % 36;
  int tid   = threadIdx.x;

  __shared__ uint64_t kk[800];
  __shared__ int      tIdx[100];
  __shared__ float    feat[100][5];
  __shared__ float    mv[5], sv[5];
  __shared__ __attribute__((aligned(16))) float ts2[600];  // pair-interleaved rows
  __shared__ __attribute__((aligned(16))) float pix[768];

  const uint64_t* kg = (const uint64_t*)key50g + (size_t)img*800;
  for(int c=tid;c<800;c+=256) kk[c] = kg[c];
  {
    const float4* cb4 = (const float4*)(in + ((size_t)img*NPIX + (size_t)chunk*256)*3);
    if(tid<192) ((float4*)pix)[tid] = cb4[tid];
  }
  __syncthreads();

  // global rank within class via binary search on 8 descending 50-lists (keys unique)
  for(int c=tid;c<800;c+=256){
    uint64_t k = kk[c];
    int cl = (c >= 400);
    int base = cl*400;
    int r = 0;
#pragma unroll
    for(int s=0;s<8;s++){
      const uint64_t* L = &kk[base + s*50];
      int lo=0, hi=50;
      while(lo<hi){ int mid=(lo+hi)>>1; if(L[mid] > k) lo=mid+1; else hi=mid; }
      r += lo;
    }
    if(r < 50) tIdx[cl*50+r] = 16383 - (int)(k & 16383u);
  }
  __syncthreads();

  // train features + stats (math + order bit-identical to the verified kmerge)
  if(tid<100){
    int pp = tIdx[tid];
    int i=pp/96, j=pp-i*96;
    const float* px = in + ((size_t)img*NPIX + pp)*3;
    for(int c=0;c<3;c++){
      float ip=clip01_div255(px[c]);
      feat[tid][c]=ip/255.0f;
    }
    feat[tid][3]=((float)i/96.0f)*100.0f;
    feat[tid][4]=((float)j/96.0f)*100.0f;
  }
  __syncthreads();
  if(tid<5){
    float s=0.f;
    for(int r=0;r<100;r++) s=s+feat[r][tid];
    float mu=s/100.0f; mv[tid]=mu;
    float v=0.f;
    for(int r=0;r<100;r++){ float d=feat[r][tid]-mu; float q=d*d; v=v+q; }
    sv[tid]=sqrtf(v/100.0f);
  }
  __syncthreads();
  // pair-interleaved layout: f_k of row r at [pair*12 + 2k + (r&1)], pair=r>>1
  if(tid<100){
    float r0=(feat[tid][0]-mv[0])/sv[0];
    float r1=(feat[tid][1]-mv[1])/sv[1];
    float r2=(feat[tid][2]-mv[2])/sv[2];
    float r3=(feat[tid][3]-mv[3])/sv[3];
    float r4=(feat[tid][4]-mv[4])/sv[4];
    float* dst = ts2 + (tid>>1)*12 + (tid&1);
    dst[0]=r0; dst[2]=r1; dst[4]=r2; dst[6]=r3; dst[8]=r4;
  }
  __syncthreads();

  // ---- knn phase (bit-identical math to the verified kknn) ----
  int p = chunk*256+tid;
  int i=p/96, j=p-i*96;
  float ip0=clip01_div255(pix[tid*3+0]);
  float ip1=clip01_div255(pix[tid*3+1]);
  float ip2=clip01_div255(pix[tid*3+2]);
  float t0,t1,t2,t3,t4;
  {
    float f0=ip0/255.0f, f1=ip1/255.0f, f2=ip2/255.0f;
    float f3=((float)i/96.0f)*100.0f, f4=((float)j/96.0f)*100.0f;
    t0=(f0-mv[0])/sv[0]; t1=(f1-mv[1])/sv[1]; t2=(f2-mv[2])/sv[2];
    t3=(f3-mv[3])/sv[3]; t4=(f4-mv[4])/sv[4];
  }

  // fg pairs 0..24 (rows 0..49): packed top-2 via min/max insertion network
  float a0x=1e30f,a0y=1e30f, a1x=1e30f,a1y=1e30f;
#pragma unroll 5
  for(int pr=0;pr<25;pr++){
    const float* tp = &ts2[pr*12];
    float4 qA = *(const float4*)(tp);    // f0(x,y) f1(x,y)
    float4 qB = *(const float4*)(tp+4);  // f2(x,y) f3(x,y)
    float2 qC = *(const float2*)(tp+8);  // f4(x,y)
    float sx, sy;
    { float dx=t0-qA.x, dy=t0-qA.y; sx=dx*dx; sy=dy*dy; }
    { float dx=t1-qA.z, dy=t1-qA.w; float wx=dx*dx, wy=dy*dy; sx=sx+wx; sy=sy+wy; }
    { float dx=t2-qB.x, dy=t2-qB.y; float wx=dx*dx, wy=dy*dy; sx=sx+wx; sy=sy+wy; }
    { float dx=t3-qB.z, dy=t3-qB.w; float wx=dx*dx, wy=dy*dy; sx=sx+wx; sy=sy+wy; }
    { float dx=t4-qC.x, dy=t4-qC.y; float wx=dx*dx, wy=dy*dy; sx=sx+wx; sy=sy+wy; }
    float tx=fmaxf(a0x,sx), ty=fmaxf(a0y,sy);
    a0x=fminf(a0x,sx);      a0y=fminf(a0y,sy);
    a1x=fminf(a1x,tx);      a1y=fminf(a1y,ty);
  }
  // exact 2nd-smallest of union of the two sorted pairs (bitonic split)
  float a1 = fmaxf(fminf(a0x,a1y), fminf(a1x,a0y));

  // bg pairs 25..49 (rows 50..99): packed top-4 insertion network
  float b0x=1e30f,b0y=1e30f, b1x=1e30f,b1y=1e30f;
  float b2x=1e30f,b2y=1e30f, b3x=1e30f,b3y=1e30f;
#pragma unroll 5
  for(int pr=25;pr<50;pr++){
    const float* tp = &ts2[pr*12];
    float4 qA = *(const float4*)(tp);
    float4 qB = *(const float4*)(tp+4);
    float2 qC = *(const float2*)(tp+8);
    float sx, sy;
    { float dx=t0-qA.x, dy=t0-qA.y; sx=dx*dx; sy=dy*dy; }
    { float dx=t1-qA.z, dy=t1-qA.w; float wx=dx*dx, wy=dy*dy; sx=sx+wx; sy=sy+wy; }
    { float dx=t2-qB.x, dy=t2-qB.y; float wx=dx*dx, wy=dy*dy; sx=sx+wx; sy=sy+wy; }
    { float dx=t3-qB.z, dy=t3-qB.w; float wx=dx*dx, wy=dy*dy; sx=sx+wx; sy=sy+wy; }
    { float dx=t4-qC.x, dy=t4-qC.y; float wx=dx*dx, wy=dy*dy; sx=sx+wx; sy=sy+wy; }
    float u0x=fmaxf(b0x,sx), u0y=fmaxf(b0y,sy);
    b0x=fminf(b0x,sx);       b0y=fminf(b0y,sy);
    float u1x=fmaxf(b1x,u0x), u1y=fmaxf(b1y,u0y);
    b1x=fminf(b1x,u0x);       b1y=fminf(b1y,u0y);
    float u2x=fmaxf(b2x,u1x), u2y=fmaxf(b2y,u1y);
    b2x=fminf(b2x,u1x);       b2y=fminf(b2y,u1y);
    b3x=fminf(b3x,u2x);       b3y=fminf(b3y,u2y);
  }
  // exact 4th-smallest of union of two sorted quads (bitonic lower-half merge)
  float l0=fminf(b0x,b3y), l1=fminf(b1x,b2y), l2=fminf(b2x,b1y), l3=fminf(b3x,b0y);
  float b3 = fmaxf(fmaxf(l0,l1), fmaxf(l2,l3));

  // seg <=> 2nd-smallest fg sqrt-dist <= 4th-smallest bg sqrt-dist (fg wins ties)
  bool seg = sqrtf(a1) <= sqrtf(b3);
  __syncthreads();                       // pix reuse fence
  pix[tid*3+0]=seg?ip0:0.f;
  pix[tid*3+1]=seg?ip1:0.f;
  pix[tid*3+2]=seg?ip2:0.f;
  __syncthreads();
  float4* ob4 = (float4*)(out + ((size_t)img*NPIX + (size_t)chunk*256)*3);
  if(tid<192) ob4[tid] = ((float4*)pix)[tid];
}

extern "C" void kernel_launch(void* const* d_in, const int* in_sizes, int n_in,
                              void* d_out, int out_size, void* d_ws, size_t ws_size,
                              hipStream_t stream) {
  const float* in = (const float*)d_in[0];
  float* out = (float*)d_out;
  unsigned long long* key50g = (unsigned long long*)d_ws;  // 204800 B

  kscore<<<512,  256, 0, stream>>>(in, key50g);
  kmknn <<<1152, 256, 0, stream>>>(in, key50g, out);
}

// Round 3
// 117.633 us; speedup vs baseline: 1.1374x; 1.1374x over previous
//
#include <hip/hip_runtime.h>
#include <stdint.h>

#define NPIX 9216   // 96*96
#define NIMG 32

// ---------- JAX threefry2x32 (20 rounds), bit-exact (verified rounds 1-12) ----------
__device__ __forceinline__ uint32_t rotl32(uint32_t x, int d){ return (x<<d)|(x>>(32-d)); }

__device__ __forceinline__ void threefry(uint32_t k0, uint32_t k1, uint32_t x0, uint32_t x1,
                                         uint32_t &o0, uint32_t &o1){
  uint32_t ks2 = k0 ^ k1 ^ 0x1BD11BDAu;
  x0 += k0; x1 += k1;
  x0+=x1; x1=rotl32(x1,13); x1^=x0;
  x0+=x1; x1=rotl32(x1,15); x1^=x0;
  x0+=x1; x1=rotl32(x1,26); x1^=x0;
  x0+=x1; x1=rotl32(x1,6);  x1^=x0;
  x0+=k1; x1+=ks2+1u;
  x0+=x1; x1=rotl32(x1,17); x1^=x0;
  x0+=x1; x1=rotl32(x1,29); x1^=x0;
  x0+=x1; x1=rotl32(x1,16); x1^=x0;
  x0+=x1; x1=rotl32(x1,24); x1^=x0;
  x0+=ks2; x1+=k0+2u;
  x0+=x1; x1=rotl32(x1,13); x1^=x0;
  x0+=x1; x1=rotl32(x1,15); x1^=x0;
  x0+=x1; x1=rotl32(x1,26); x1^=x0;
  x0+=x1; x1=rotl32(x1,6);  x1^=x0;
  x0+=k0; x1+=k1+3u;
  x0+=x1; x1=rotl32(x1,17); x1^=x0;
  x0+=x1; x1=rotl32(x1,29); x1^=x0;
  x0+=x1; x1=rotl32(x1,16); x1^=x0;
  x0+=x1; x1=rotl32(x1,24); x1^=x0;
  x0+=k1; x1+=ks2+4u;
  x0+=x1; x1=rotl32(x1,13); x1^=x0;
  x0+=x1; x1=rotl32(x1,15); x1^=x0;
  x0+=x1; x1=rotl32(x1,26); x1^=x0;
  x0+=x1; x1=rotl32(x1,6);  x1^=x0;
  x0+=ks2; x1+=k0+5u;
  o0=x0; o1=x1;
}

__device__ __forceinline__ float clip01_div255(float x){
  return fminf(fmaxf(x/255.0f, 0.0f), 1.0f);
}

// ---------- K1: 32 blocks x 1024 threads -- ONE BLOCK PER IMAGE does everything
// before KNN: channel max, scoring (1 threefry/pixel: only its own class's key),
// whole-image top-50 per class (exactly equivalent to the strip-merge: any global
// top-50 key is in its strip's top-50; keys unique; reference IS whole-image top_k),
// then the verbatim kmerge feature/stats/standardize tail (identical summation
// order -> bit-identical). No cross-block producer->consumer edges (round-2 lesson);
// no redundant per-block recompute (round-1 lesson). Replaces kmax+kscore+kmerge.
__global__ __launch_bounds__(1024) void kprep(const float* __restrict__ in,
                                              float* __restrict__ ts2g,      // [32][600]
                                              float* __restrict__ meanstd){  // [32][10]
#pragma clang fp contract(off)
  int img = blockIdx.x;
  int tid = threadIdx.x;

  __shared__ uint32_t vvL[NPIX];          // vv | (fg<<31)
  __shared__ uint64_t cand[2048];         // per-class candidate keys (sequential reuse)
  __shared__ int      hist[2][129];
  __shared__ int      nc, bbinL[2];
  __shared__ float    cmaxL[3];
  __shared__ float    wred[3][16];
  __shared__ int      tIdx[100];
  __shared__ float    feat[100][5];
  __shared__ float    mv[5], sv[5];

  if(tid<258) ((int*)hist)[tid]=0;

  const float* p = in + (size_t)img*NPIX*3;

  // ---- channel max (strided, coalesced; fmax exactly associative -> bit-identical)
  {
    float m0=0.f, m1=0.f, m2=0.f;
    for(int k=0;k<9;k++){
      int px = k*1024 + tid;
      m0 = fmaxf(m0, clip01_div255(p[px*3+0]));
      m1 = fmaxf(m1, clip01_div255(p[px*3+1]));
      m2 = fmaxf(m2, clip01_div255(p[px*3+2]));
    }
    for(int off=32; off>0; off>>=1){
      m0 = fmaxf(m0, __shfl_down(m0,off));
      m1 = fmaxf(m1, __shfl_down(m1,off));
      m2 = fmaxf(m2, __shfl_down(m2,off));
    }
    int lane = tid & 63, wv = tid >> 6;
    if(lane==0){ wred[0][wv]=m0; wred[1][wv]=m1; wred[2][wv]=m2; }
  }
  __syncthreads();
  if(tid<3){
    float m = wred[tid][0];
    for(int w=1;w<16;w++) m = fmaxf(m, wred[tid][w]);
    cmaxL[tid]=m;
  }
  __syncthreads();
  float c0=cmaxL[0], c1=cmaxL[1], c2=cmaxL[2];

  // ---- partitionable threefry keys (bit-exact, verbatim derivation)
  uint32_t ik0, ik1; threefry(0u, 42u, 0u, (uint32_t)img, ik0, ik1);
  uint32_t sf0, sf1; threefry(ik0, ik1, 0u, 0u, sf0, sf1);   // cls=0 (fg)
  uint32_t sb0, sb1; threefry(ik0, ik1, 0u, 1u, sb0, sb1);   // cls=1 (bg)

  // ---- score: 1 threefry per pixel with its OWN class key (half baseline's work);
  // valid-only dual histogram (vv>=1 always for the owning class)
  for(int k=0;k<9;k++){
    int px = k*1024 + tid;
    float a  = clip01_div255(p[px*3+0])/c0;
    float bb = clip01_div255(p[px*3+1])/c1;
    float c  = clip01_div255(p[px*3+2])/c2;
    bool fg = (a>0.f && a<0.6f) || (bb>0.f && bb<0.6f) || (c>0.f && c<0.6f);
    uint32_t k0 = fg ? sf0 : sb0, k1 = fg ? sf1 : sb1;
    uint32_t r1, r2; threefry(k0, k1, 0u, (uint32_t)px, r1, r2);
    uint32_t vv = ((r1 ^ r2) >> 9) + 1u;       // monotone in uniform
    vvL[px] = vv | (fg ? 0x80000000u : 0u);
    atomicAdd(&hist[fg?0:1][vv>>16], 1);
  }
  __syncthreads();

  // ---- bbin per class = largest bin with valid-suffix >= 50 (verified wave scan;
  // wave 0 -> fg, wave 1 -> bg)
  if(tid<128){
    int cls = tid>>6, l = tid&63;
    int h0 = hist[cls][2*l];
    int h1 = hist[cls][2*l+1];
    int h128 = hist[cls][128];
    int S = h0 + h1;
    for(int off=1; off<64; off<<=1){
      int o = __shfl_down(S, off);
      if(l + off < 64) S += o;
    }
    int ss0 = S + h128;
    int ss1 = S - h0 + h128;
    int cd = -1;
    if(ss0 >= 50) cd = 2*l;
    if(ss1 >= 50) cd = 2*l+1;
    if(l==63 && h128 >= 50) cd = 128;
    for(int off=32; off>0; off>>=1){
      int o = __shfl_down(cd, off);
      cd = o > cd ? o : cd;
    }
    if(l==0) bbinL[cls] = cd;
  }
  __syncthreads();

  // ---- per-class (sequential; cand reused): compact valid candidates, exact rank.
  // Valid-only filter is exact: when bbin>=0 the 50 winners are all valid by bbin's
  // definition (valid suffix >= 50); when bbin==-1 (<50 valid) ranks 0..m-1 are the
  // valid keys desc, then ranks fill with smallest-index other-class pixels, matching
  // top_k's -1.0 tie order (verified semantics).
  for(int cls=0; cls<2; cls++){
    if(tid==0) nc=0;
    __syncthreads();
    int bb = bbinL[cls];
    uint32_t want = (cls==0) ? 0x80000000u : 0u;
    for(int k=0;k<9;k++){
      int px = k*1024 + tid;
      uint32_t w = vvL[px];
      if((w & 0x80000000u) == want){
        uint32_t vv = w & 0x7FFFFFFFu;
        if((int)(vv>>16) >= bb){
          int pos = atomicAdd(&nc,1);
          if(pos < 2048)                       // threefry-uniform bound: m ~ 50-200
            cand[pos] = ((uint64_t)vv << 14) | (uint64_t)(16383 - px);
        }
      }
    }
    __syncthreads();
    int m = nc; if(m > 2048) m = 2048;
    for(int c=tid; c<m; c+=1024){
      uint64_t kk = cand[c];
      int r = 0, j = 0;
      while(j < m){                            // chunked early-exit: exact for r<50
        int je = j+64 < m ? j+64 : m;
        for(; j<je; j++) r += (cand[j] > kk);
        if(r >= 50) break;
      }
      if(r < 50) tIdx[cls*50 + r] = 16383 - (int)(kk & 16383u);
    }
    __syncthreads();
    if(bb == -1){                              // <50 valid: fill with ascending-index
      if(tid==0){                              // other-class pixels (top_k tie order)
        int need = 50 - m, r = m;
        for(int px=0; px<NPIX && need>0; px++){
          if((vvL[px] & 0x80000000u) != want){ tIdx[cls*50 + r] = px; r++; need--; }
        }
      }
      __syncthreads();                         // uniform branch (bb is block-uniform)
    }
  }

  // ---- train features + stats (verbatim kmerge: identical summation order)
  if(tid<100){
    int pp = tIdx[tid];
    int i=pp/96, j=pp-i*96;
    const float* px = in + ((size_t)img*NPIX + pp)*3;
    for(int c=0;c<3;c++){
      float ip=clip01_div255(px[c]);
      feat[tid][c]=ip/255.0f;
    }
    feat[tid][3]=((float)i/96.0f)*100.0f;
    feat[tid][4]=((float)j/96.0f)*100.0f;
  }
  __syncthreads();
  if(tid<5){
    float s=0.f;
    for(int r=0;r<100;r++) s=s+feat[r][tid];
    float mu=s/100.0f; mv[tid]=mu;
    float v=0.f;
    for(int r=0;r<100;r++){ float d=feat[r][tid]-mu; float q=d*d; v=v+q; }
    sv[tid]=sqrtf(v/100.0f);
  }
  __syncthreads();
  // pair-interleaved layout: f_k of row r at [pair*12 + 2k + (r&1)], pair=r>>1
  if(tid<100){
    float r0=(feat[tid][0]-mv[0])/sv[0];
    float r1=(feat[tid][1]-mv[1])/sv[1];
    float r2=(feat[tid][2]-mv[2])/sv[2];
    float r3=(feat[tid][3]-mv[3])/sv[3];
    float r4=(feat[tid][4]-mv[4])/sv[4];
    float* dst = ts2g + img*600 + (tid>>1)*12 + (tid&1);
    dst[0]=r0; dst[2]=r1; dst[4]=r2; dst[6]=r3; dst[8]=r4;
  }
  if(tid<5)       meanstd[img*10+tid]=mv[tid];
  else if(tid<10) meanstd[img*10+tid]=sv[tid-5];
}

// ---------- K2: 1152 blocks: 5-NN, packed-pair min/max insertion networks
// (verbatim the verified baseline kknn) ----
__global__ __launch_bounds__(256) void kknn(const float* __restrict__ in,
                                            const float* __restrict__ ts2g,
                                            const float* __restrict__ meanstd,
                                            float* __restrict__ out){
#pragma clang fp contract(off)
  int b     = blockIdx.x;
  int img   = b / 36;
  int chunk = b % 36;
  int tid   = threadIdx.x;

  __shared__ float    mv[5], sv[5];
  __shared__ __attribute__((aligned(16))) float ts2[600];  // pair-interleaved rows
  __shared__ __attribute__((aligned(16))) float pix[768];

  if(tid<150) ((float4*)ts2)[tid] = ((const float4*)(ts2g + img*600))[tid];
  if(tid>=192 && tid<197) mv[tid-192]=meanstd[img*10+(tid-192)];
  if(tid>=224 && tid<229) sv[tid-224]=meanstd[img*10+5+(tid-224)];
  {
    const float4* cb4 = (const float4*)(in + ((size_t)img*NPIX + (size_t)chunk*256)*3);
    if(tid<192) ((float4*)pix)[tid] = cb4[tid];
  }
  __syncthreads();

  // test feature for own pixel (bit-identical math)
  int p = chunk*256+tid;
  int i=p/96, j=p-i*96;
  float ip0=clip01_div255(pix[tid*3+0]);
  float ip1=clip01_div255(pix[tid*3+1]);
  float ip2=clip01_div255(pix[tid*3+2]);
  float t0,t1,t2,t3,t4;
  {
    float f0=ip0/255.0f, f1=ip1/255.0f, f2=ip2/255.0f;
    float f3=((float)i/96.0f)*100.0f, f4=((float)j/96.0f)*100.0f;
    t0=(f0-mv[0])/sv[0]; t1=(f1-mv[1])/sv[1]; t2=(f2-mv[2])/sv[2];
    t3=(f3-mv[3])/sv[3]; t4=(f4-mv[4])/sv[4];
  }

  // fg pairs 0..24 (rows 0..49): packed top-2 via min/max insertion network.
  float a0x=1e30f,a0y=1e30f, a1x=1e30f,a1y=1e30f;
#pragma unroll 5
  for(int pr=0;pr<25;pr++){
    const float* tp = &ts2[pr*12];
    float4 qA = *(const float4*)(tp);    // f0(x,y) f1(x,y)
    float4 qB = *(const float4*)(tp+4);  // f2(x,y) f3(x,y)
    float2 qC = *(const float2*)(tp+8);  // f4(x,y)
    float sx, sy;
    { float dx=t0-qA.x, dy=t0-qA.y; sx=dx*dx; sy=dy*dy; }
    { float dx=t1-qA.z, dy=t1-qA.w; float wx=dx*dx, wy=dy*dy; sx=sx+wx; sy=sy+wy; }
    { float dx=t2-qB.x, dy=t2-qB.y; float wx=dx*dx, wy=dy*dy; sx=sx+wx; sy=sy+wy; }
    { float dx=t3-qB.z, dy=t3-qB.w; float wx=dx*dx, wy=dy*dy; sx=sx+wx; sy=sy+wy; }
    { float dx=t4-qC.x, dy=t4-qC.y; float wx=dx*dx, wy=dy*dy; sx=sx+wx; sy=sy+wy; }
    float tx=fmaxf(a0x,sx), ty=fmaxf(a0y,sy);
    a0x=fminf(a0x,sx);      a0y=fminf(a0y,sy);
    a1x=fminf(a1x,tx);      a1y=fminf(a1y,ty);
  }
  // exact 2nd-smallest of union of the two sorted pairs (bitonic split)
  float a1 = fmaxf(fminf(a0x,a1y), fminf(a1x,a0y));

  // bg pairs 25..49 (rows 50..99): packed top-4 insertion network
  float b0x=1e30f,b0y=1e30f, b1x=1e30f,b1y=1e30f;
  float b2x=1e30f,b2y=1e30f, b3x=1e30f,b3y=1e30f;
#pragma unroll 5
  for(int pr=25;pr<50;pr++){
    const float* tp = &ts2[pr*12];
    float4 qA = *(const float4*)(tp);
    float4 qB = *(const float4*)(tp+4);
    float2 qC = *(const float2*)(tp+8);
    float sx, sy;
    { float dx=t0-qA.x, dy=t0-qA.y; sx=dx*dx; sy=dy*dy; }
    { float dx=t1-qA.z, dy=t1-qA.w; float wx=dx*dx, wy=dy*dy; sx=sx+wx; sy=sy+wy; }
    { float dx=t2-qB.x, dy=t2-qB.y; float wx=dx*dx, wy=dy*dy; sx=sx+wx; sy=sy+wy; }
    { float dx=t3-qB.z, dy=t3-qB.w; float wx=dx*dx, wy=dy*dy; sx=sx+wx; sy=sy+wy; }
    { float dx=t4-qC.x, dy=t4-qC.y; float wx=dx*dx, wy=dy*dy; sx=sx+wx; sy=sy+wy; }
    float u0x=fmaxf(b0x,sx), u0y=fmaxf(b0y,sy);
    b0x=fminf(b0x,sx);       b0y=fminf(b0y,sy);
    float u1x=fmaxf(b1x,u0x), u1y=fmaxf(b1y,u0y);
    b1x=fminf(b1x,u0x);       b1y=fminf(b1y,u0y);
    float u2x=fmaxf(b2x,u1x), u2y=fmaxf(b2y,u1y);
    b2x=fminf(b2x,u1x);       b2y=fminf(b2y,u1y);
    b3x=fminf(b3x,u2x);       b3y=fminf(b3y,u2y);
  }
  // exact 4th-smallest of union of two sorted quads (bitonic lower-half merge)
  float l0=fminf(b0x,b3y), l1=fminf(b1x,b2y), l2=fminf(b2x,b1y), l3=fminf(b3x,b0y);
  float b3 = fmaxf(fmaxf(l0,l1), fmaxf(l2,l3));

  // seg <=> 2nd-smallest fg sqrt-dist <= 4th-smallest bg sqrt-dist (fg wins ties)
  bool seg = sqrtf(a1) <= sqrtf(b3);
  __syncthreads();                       // pix reuse fence
  pix[tid*3+0]=seg?ip0:0.f;
  pix[tid*3+1]=seg?ip1:0.f;
  pix[tid*3+2]=seg?ip2:0.f;
  __syncthreads();
  float4* ob4 = (float4*)(out + ((size_t)img*NPIX + (size_t)chunk*256)*3);
  if(tid<192) ob4[tid] = ((float4*)pix)[tid];
}

extern "C" void kernel_launch(void* const* d_in, const int* in_sizes, int n_in,
                              void* d_out, int out_size, void* d_ws, size_t ws_size,
                              hipStream_t stream) {
  const float* in = (const float*)d_in[0];
  float* out = (float*)d_out;
  float* ts2g    = (float*)d_ws;                         // 76800 B
  float* meanstd = (float*)((char*)d_ws + 76800);        // 1280 B

  kprep<<<32,   1024, 0, stream>>>(in, ts2g, meanstd);
  kknn <<<1152, 256,  0, stream>>>(in, ts2g, meanstd, out);
}

// Round 4
// 108.386 us; speedup vs baseline: 1.2344x; 1.0853x over previous
//
#include <hip/hip_runtime.h>
#include <stdint.h>

#define NPIX 9216   // 96*96
#define NIMG 32

// ---------- JAX threefry2x32 (20 rounds), bit-exact (verified rounds 1-12) ----------
__device__ __forceinline__ uint32_t rotl32(uint32_t x, int d){ return (x<<d)|(x>>(32-d)); }

__device__ __forceinline__ void threefry(uint32_t k0, uint32_t k1, uint32_t x0, uint32_t x1,
                                         uint32_t &o0, uint32_t &o1){
  uint32_t ks2 = k0 ^ k1 ^ 0x1BD11BDAu;
  x0 += k0; x1 += k1;
  x0+=x1; x1=rotl32(x1,13); x1^=x0;
  x0+=x1; x1=rotl32(x1,15); x1^=x0;
  x0+=x1; x1=rotl32(x1,26); x1^=x0;
  x0+=x1; x1=rotl32(x1,6);  x1^=x0;
  x0+=k1; x1+=ks2+1u;
  x0+=x1; x1=rotl32(x1,17); x1^=x0;
  x0+=x1; x1=rotl32(x1,29); x1^=x0;
  x0+=x1; x1=rotl32(x1,16); x1^=x0;
  x0+=x1; x1=rotl32(x1,24); x1^=x0;
  x0+=ks2; x1+=k0+2u;
  x0+=x1; x1=rotl32(x1,13); x1^=x0;
  x0+=x1; x1=rotl32(x1,15); x1^=x0;
  x0+=x1; x1=rotl32(x1,26); x1^=x0;
  x0+=x1; x1=rotl32(x1,6);  x1^=x0;
  x0+=k0; x1+=k1+3u;
  x0+=x1; x1=rotl32(x1,17); x1^=x0;
  x0+=x1; x1=rotl32(x1,29); x1^=x0;
  x0+=x1; x1=rotl32(x1,16); x1^=x0;
  x0+=x1; x1=rotl32(x1,24); x1^=x0;
  x0+=k1; x1+=ks2+4u;
  x0+=x1; x1=rotl32(x1,13); x1^=x0;
  x0+=x1; x1=rotl32(x1,15); x1^=x0;
  x0+=x1; x1=rotl32(x1,26); x1^=x0;
  x0+=x1; x1=rotl32(x1,6);  x1^=x0;
  x0+=ks2; x1+=k0+5u;
  o0=x0; o1=x1;
}

__device__ __forceinline__ float clip01_div255(float x){
  return fminf(fmaxf(x/255.0f, 0.0f), 1.0f);
}

// ---------- K1: 32 blocks x 1024 threads, ONE BLOCK PER IMAGE (round-3 verified
// structure & math). Round-4 changes are ACCESS-PATTERN ONLY:
//  * single vectorized global pass: 3 float4/thread-group (4 pixels), held in
//    registers (static unroll); max pass + score pass both feed from these regs
//    (round 3 did 2 passes x 27648 stride-3 scalar loads -> 3.4% VALUBusy)
//  * both classes compacted in ONE vvL sweep; ranking split half-block per class
// All selection semantics, float op order, threefry usage: verbatim round 3.
__global__ __launch_bounds__(1024) void kprep(const float* __restrict__ in,
                                              float* __restrict__ ts2g,      // [32][600]
                                              float* __restrict__ meanstd){  // [32][10]
#pragma clang fp contract(off)
  int img = blockIdx.x;
  int tid = threadIdx.x;

  __shared__ uint32_t vvL[NPIX];          // vv | (fg<<31)
  __shared__ uint64_t cand[2][1024];      // per-class candidates (m<=~200 when bbin>=0,
  __shared__ int      ncA[2];             //  <50 when bbin==-1 -> cap 1024 safe)
  __shared__ int      hist[2][129];
  __shared__ int      bbinL[2];
  __shared__ float    cmaxL[3];
  __shared__ float    wred[3][16];
  __shared__ int      tIdx[100];
  __shared__ float    feat[100][5];
  __shared__ float    mv[5], sv[5];

  if(tid<258) ((int*)hist)[tid]=0;
  if(tid<2)   ncA[tid]=0;

  const float* p = in + (size_t)img*NPIX*3;
  const float4* ip4 = (const float4*)p;

  // ---- single vectorized pass: each thread-group-slot owns 4 pixels (3 float4).
  // 2304 groups; k=0,1 full, k=2 only tid<256. Indices all static after unroll.
  float4 rv[3][3];
  float m0=0.f, m1=0.f, m2=0.f;
#pragma unroll
  for(int k=0;k<3;k++){
    int g = k*1024 + tid;
    if(g < 2304){
      float4 v0 = ip4[3*g+0], v1 = ip4[3*g+1], v2 = ip4[3*g+2];
      rv[k][0]=v0; rv[k][1]=v1; rv[k][2]=v2;
      // channel max (fmax exactly associative/commutative -> bit-identical fold)
      m0 = fmaxf(m0, fmaxf(fmaxf(clip01_div255(v0.x), clip01_div255(v0.w)),
                           fmaxf(clip01_div255(v1.z), clip01_div255(v2.y))));
      m1 = fmaxf(m1, fmaxf(fmaxf(clip01_div255(v0.y), clip01_div255(v1.x)),
                           fmaxf(clip01_div255(v1.w), clip01_div255(v2.z))));
      m2 = fmaxf(m2, fmaxf(fmaxf(clip01_div255(v0.z), clip01_div255(v1.y)),
                           fmaxf(clip01_div255(v2.x), clip01_div255(v2.w))));
    }
  }
  for(int off=32; off>0; off>>=1){
    m0 = fmaxf(m0, __shfl_down(m0,off));
    m1 = fmaxf(m1, __shfl_down(m1,off));
    m2 = fmaxf(m2, __shfl_down(m2,off));
  }
  { int lane = tid & 63, wv = tid >> 6;
    if(lane==0){ wred[0][wv]=m0; wred[1][wv]=m1; wred[2][wv]=m2; } }
  __syncthreads();
  if(tid<3){
    float m = wred[tid][0];
    for(int w=1;w<16;w++) m = fmaxf(m, wred[tid][w]);
    cmaxL[tid]=m;
  }
  __syncthreads();
  float c0=cmaxL[0], c1=cmaxL[1], c2=cmaxL[2];

  // ---- partitionable threefry keys (bit-exact, verbatim)
  uint32_t ik0, ik1; threefry(0u, 42u, 0u, (uint32_t)img, ik0, ik1);
  uint32_t sf0, sf1; threefry(ik0, ik1, 0u, 0u, sf0, sf1);   // cls=0 (fg)
  uint32_t sb0, sb1; threefry(ik0, ik1, 0u, 1u, sb0, sb1);   // cls=1 (bg)

  // ---- score from REGISTERS (zero reloads); math verbatim round 3
  auto score_px = [&](int px, float pa, float pb, float pc){
    float a  = clip01_div255(pa)/c0;
    float bb = clip01_div255(pb)/c1;
    float c  = clip01_div255(pc)/c2;
    bool fg = (a>0.f && a<0.6f) || (bb>0.f && bb<0.6f) || (c>0.f && c<0.6f);
    uint32_t k0 = fg ? sf0 : sb0, k1 = fg ? sf1 : sb1;
    uint32_t r1, r2; threefry(k0, k1, 0u, (uint32_t)px, r1, r2);
    uint32_t vv = ((r1 ^ r2) >> 9) + 1u;       // monotone in uniform
    vvL[px] = vv | (fg ? 0x80000000u : 0u);
    atomicAdd(&hist[fg?0:1][vv>>16], 1);
  };
#pragma unroll
  for(int k=0;k<3;k++){
    int g = k*1024 + tid;
    if(g < 2304){
      float4 v0=rv[k][0], v1=rv[k][1], v2=rv[k][2];
      int pb = g*4;
      score_px(pb+0, v0.x, v0.y, v0.z);
      score_px(pb+1, v0.w, v1.x, v1.y);
      score_px(pb+2, v1.z, v1.w, v2.x);
      score_px(pb+3, v2.y, v2.z, v2.w);
    }
  }
  __syncthreads();

  // ---- bbin per class = largest bin with valid-suffix >= 50 (verified wave scan;
  // wave 0 -> fg, wave 1 -> bg)
  if(tid<128){
    int cls = tid>>6, l = tid&63;
    int h0 = hist[cls][2*l];
    int h1 = hist[cls][2*l+1];
    int h128 = hist[cls][128];
    int S = h0 + h1;
    for(int off=1; off<64; off<<=1){
      int o = __shfl_down(S, off);
      if(l + off < 64) S += o;
    }
    int ss0 = S + h128;
    int ss1 = S - h0 + h128;
    int cd = -1;
    if(ss0 >= 50) cd = 2*l;
    if(ss1 >= 50) cd = 2*l+1;
    if(l==63 && h128 >= 50) cd = 128;
    for(int off=32; off>0; off>>=1){
      int o = __shfl_down(cd, off);
      cd = o > cd ? o : cd;
    }
    if(l==0) bbinL[cls] = cd;
  }
  __syncthreads();

  // ---- BOTH classes compacted in one vvL sweep (semantics verbatim round 3)
  {
    int bb0 = bbinL[0], bb1 = bbinL[1];
    for(int k=0;k<9;k++){
      int px = k*1024 + tid;
      uint32_t w = vvL[px];
      int cls = (w & 0x80000000u) ? 0 : 1;
      uint32_t vv = w & 0x7FFFFFFFu;
      int bb = cls ? bb1 : bb0;
      if((int)(vv>>16) >= bb){
        int pos = atomicAdd(&ncA[cls],1);
        if(pos < 1024)
          cand[cls][pos] = ((uint64_t)vv << 14) | (uint64_t)(16383 - px);
      }
    }
  }
  __syncthreads();

  // ---- rank: half-block per class (chunked early-exit, exact for r<50; verbatim)
  {
    int cls = (tid >= 512);
    int lt  = tid & 511;
    int m = ncA[cls]; if(m > 1024) m = 1024;
    const uint64_t* C = cand[cls];
    for(int c=lt; c<m; c+=512){
      uint64_t kk = C[c];
      int r = 0, j = 0;
      while(j < m){
        int je = j+64 < m ? j+64 : m;
        for(; j<je; j++) r += (C[j] > kk);
        if(r >= 50) break;
      }
      if(r < 50) tIdx[cls*50 + r] = 16383 - (int)(kk & 16383u);
    }
  }
  __syncthreads();

  // ---- <50-valid fallback (verbatim round-3 semantics; block-uniform branches)
  for(int cls=0; cls<2; cls++){
    if(bbinL[cls] == -1){
      uint32_t want = (cls==0) ? 0x80000000u : 0u;
      if(tid==0){
        int m = ncA[cls];                    // bbin==-1 -> m = class count < 50
        int need = 50 - m, r = m;
        for(int px=0; px<NPIX && need>0; px++){
          if((vvL[px] & 0x80000000u) != want){ tIdx[cls*50 + r] = px; r++; need--; }
        }
      }
      __syncthreads();
    }
  }

  // ---- train features + stats (verbatim: identical summation order)
  if(tid<100){
    int pp = tIdx[tid];
    int i=pp/96, j=pp-i*96;
    const float* px = in + ((size_t)img*NPIX + pp)*3;
    for(int c=0;c<3;c++){
      float ip=clip01_div255(px[c]);
      feat[tid][c]=ip/255.0f;
    }
    feat[tid][3]=((float)i/96.0f)*100.0f;
    feat[tid][4]=((float)j/96.0f)*100.0f;
  }
  __syncthreads();
  if(tid<5){
    float s=0.f;
    for(int r=0;r<100;r++) s=s+feat[r][tid];
    float mu=s/100.0f; mv[tid]=mu;
    float v=0.f;
    for(int r=0;r<100;r++){ float d=feat[r][tid]-mu; float q=d*d; v=v+q; }
    sv[tid]=sqrtf(v/100.0f);
  }
  __syncthreads();
  // pair-interleaved layout: f_k of row r at [pair*12 + 2k + (r&1)], pair=r>>1
  if(tid<100){
    float r0=(feat[tid][0]-mv[0])/sv[0];
    float r1=(feat[tid][1]-mv[1])/sv[1];
    float r2=(feat[tid][2]-mv[2])/sv[2];
    float r3=(feat[tid][3]-mv[3])/sv[3];
    float r4=(feat[tid][4]-mv[4])/sv[4];
    float* dst = ts2g + img*600 + (tid>>1)*12 + (tid&1);
    dst[0]=r0; dst[2]=r1; dst[4]=r2; dst[6]=r3; dst[8]=r4;
  }
  if(tid<5)       meanstd[img*10+tid]=mv[tid];
  else if(tid<10) meanstd[img*10+tid]=sv[tid-5];
}

// ---------- K2: 1152 blocks: 5-NN, packed-pair min/max insertion networks
// (verbatim the verified baseline kknn; passed rounds 0/3) ----
__global__ __launch_bounds__(256) void kknn(const float* __restrict__ in,
                                            const float* __restrict__ ts2g,
                                            const float* __restrict__ meanstd,
                                            float* __restrict__ out){
#pragma clang fp contract(off)
  int b     = blockIdx.x;
  int img   = b / 36;
  int chunk = b % 36;
  int tid   = threadIdx.x;

  __shared__ float    mv[5], sv[5];
  __shared__ __attribute__((aligned(16))) float ts2[600];  // pair-interleaved rows
  __shared__ __attribute__((aligned(16))) float pix[768];

  if(tid<150) ((float4*)ts2)[tid] = ((const float4*)(ts2g + img*600))[tid];
  if(tid>=192 && tid<197) mv[tid-192]=meanstd[img*10+(tid-192)];
  if(tid>=224 && tid<229) sv[tid-224]=meanstd[img*10+5+(tid-224)];
  {
    const float4* cb4 = (const float4*)(in + ((size_t)img*NPIX + (size_t)chunk*256)*3);
    if(tid<192) ((float4*)pix)[tid] = cb4[tid];
  }
  __syncthreads();

  // test feature for own pixel (bit-identical math)
  int p = chunk*256+tid;
  int i=p/96, j=p-i*96;
  float ip0=clip01_div255(pix[tid*3+0]);
  float ip1=clip01_div255(pix[tid*3+1]);
  float ip2=clip01_div255(pix[tid*3+2]);
  float t0,t1,t2,t3,t4;
  {
    float f0=ip0/255.0f, f1=ip1/255.0f, f2=ip2/255.0f;
    float f3=((float)i/96.0f)*100.0f, f4=((float)j/96.0f)*100.0f;
    t0=(f0-mv[0])/sv[0]; t1=(f1-mv[1])/sv[1]; t2=(f2-mv[2])/sv[2];
    t3=(f3-mv[3])/sv[3]; t4=(f4-mv[4])/sv[4];
  }

  // fg pairs 0..24 (rows 0..49): packed top-2 via min/max insertion network.
  float a0x=1e30f,a0y=1e30f, a1x=1e30f,a1y=1e30f;
#pragma unroll 5
  for(int pr=0;pr<25;pr++){
    const float* tp = &ts2[pr*12];
    float4 qA = *(const float4*)(tp);    // f0(x,y) f1(x,y)
    float4 qB = *(const float4*)(tp+4);  // f2(x,y) f3(x,y)
    float2 qC = *(const float2*)(tp+8);  // f4(x,y)
    float sx, sy;
    { float dx=t0-qA.x, dy=t0-qA.y; sx=dx*dx; sy=dy*dy; }
    { float dx=t1-qA.z, dy=t1-qA.w; float wx=dx*dx, wy=dy*dy; sx=sx+wx; sy=sy+wy; }
    { float dx=t2-qB.x, dy=t2-qB.y; float wx=dx*dx, wy=dy*dy; sx=sx+wx; sy=sy+wy; }
    { float dx=t3-qB.z, dy=t3-qB.w; float wx=dx*dx, wy=dy*dy; sx=sx+wx; sy=sy+wy; }
    { float dx=t4-qC.x, dy=t4-qC.y; float wx=dx*dx, wy=dy*dy; sx=sx+wx; sy=sy+wy; }
    float tx=fmaxf(a0x,sx), ty=fmaxf(a0y,sy);
    a0x=fminf(a0x,sx);      a0y=fminf(a0y,sy);
    a1x=fminf(a1x,tx);      a1y=fminf(a1y,ty);
  }
  // exact 2nd-smallest of union of the two sorted pairs (bitonic split)
  float a1 = fmaxf(fminf(a0x,a1y), fminf(a1x,a0y));

  // bg pairs 25..49 (rows 50..99): packed top-4 insertion network
  float b0x=1e30f,b0y=1e30f, b1x=1e30f,b1y=1e30f;
  float b2x=1e30f,b2y=1e30f, b3x=1e30f,b3y=1e30f;
#pragma unroll 5
  for(int pr=25;pr<50;pr++){
    const float* tp = &ts2[pr*12];
    float4 qA = *(const float4*)(tp);
    float4 qB = *(const float4*)(tp+4);
    float2 qC = *(const float2*)(tp+8);
    float sx, sy;
    { float dx=t0-qA.x, dy=t0-qA.y; sx=dx*dx; sy=dy*dy; }
    { float dx=t1-qA.z, dy=t1-qA.w; float wx=dx*dx, wy=dy*dy; sx=sx+wx; sy=sy+wy; }
    { float dx=t2-qB.x, dy=t2-qB.y; float wx=dx*dx, wy=dy*dy; sx=sx+wx; sy=sy+wy; }
    { float dx=t3-qB.z, dy=t3-qB.w; float wx=dx*dx, wy=dy*dy; sx=sx+wx; sy=sy+wy; }
    { float dx=t4-qC.x, dy=t4-qC.y; float wx=dx*dx, wy=dy*dy; sx=sx+wx; sy=sy+wy; }
    float u0x=fmaxf(b0x,sx), u0y=fmaxf(b0y,sy);
    b0x=fminf(b0x,sx);       b0y=fminf(b0y,sy);
    float u1x=fmaxf(b1x,u0x), u1y=fmaxf(b1y,u0y);
    b1x=fminf(b1x,u0x);       b1y=fminf(b1y,u0y);
    float u2x=fmaxf(b2x,u1x), u2y=fmaxf(b2y,u1y);
    b2x=fminf(b2x,u1x);       b2y=fminf(b2y,u1y);
    b3x=fminf(b3x,u2x);       b3y=fminf(b3y,u2y);
  }
  // exact 4th-smallest of union of two sorted quads (bitonic lower-half merge)
  float l0=fminf(b0x,b3y), l1=fminf(b1x,b2y), l2=fminf(b2x,b1y), l3=fminf(b3x,b0y);
  float b3 = fmaxf(fmaxf(l0,l1), fmaxf(l2,l3));

  // seg <=> 2nd-smallest fg sqrt-dist <= 4th-smallest bg sqrt-dist (fg wins ties)
  bool seg = sqrtf(a1) <= sqrtf(b3);
  __syncthreads();                       // pix reuse fence
  pix[tid*3+0]=seg?ip0:0.f;
  pix[tid*3+1]=seg?ip1:0.f;
  pix[tid*3+2]=seg?ip2:0.f;
  __syncthreads();
  float4* ob4 = (float4*)(out + ((size_t)img*NPIX + (size_t)chunk*256)*3);
  if(tid<192) ob4[tid] = ((float4*)pix)[tid];
}

extern "C" void kernel_launch(void* const* d_in, const int* in_sizes, int n_in,
                              void* d_out, int out_size, void* d_ws, size_t ws_size,
                              hipStream_t stream) {
  const float* in = (const float*)d_in[0];
  float* out = (float*)d_out;
  float* ts2g    = (float*)d_ws;                         // 76800 B
  float* meanstd = (float*)((char*)d_ws + 76800);        // 1280 B

  kprep<<<32,   1024, 0, stream>>>(in, ts2g, meanstd);
  kknn <<<1152, 256,  0, stream>>>(in, ts2g, meanstd, out);
}